// Round 1
// baseline (2083.883 us; speedup 1.0000x reference)
//
#include <hip/hip_runtime.h>
#include <hip/hip_bf16.h>
#include <math.h>

// Problem constants
#define NN 100000
#define EE 1600000
#define ET 1700000            // E + N self-loops
#define F_IN 128
#define HDIM 64
#define HEADS 8
#define C1 8
#define NEG_SLOPE 0.2f

// ---------- float <-> ordered uint for atomicMax on floats ----------
__device__ __forceinline__ unsigned enc_f32(float f) {
    unsigned u = __float_as_uint(f);
    return (u & 0x80000000u) ? ~u : (u | 0x80000000u);
}
__device__ __forceinline__ float dec_f32(unsigned e) {
    return (e & 0x80000000u) ? __uint_as_float(e ^ 0x80000000u)
                             : __uint_as_float(~e);
}
__device__ __forceinline__ float leaky(float v) {
    return v > 0.f ? v : NEG_SLOPE * v;
}

// ---------- GEMM1: h1[N,64] = x[N,128] @ W1[128,64] ----------
// 16 nodes per block, 256 threads: thread computes 4 (node,ch) outputs.
__global__ __launch_bounds__(256) void gemm1_kernel(
        const float* __restrict__ x, const float* __restrict__ W1,
        float* __restrict__ h1) {
    __shared__ float ws[128 * 64];   // 32 KB
    __shared__ float xs[16 * 128];   // 8 KB
    const int tid = threadIdx.x;
    const int node0 = blockIdx.x * 16;
    for (int i = tid; i < 128 * 64; i += 256) ws[i] = W1[i];
    for (int i = tid; i < 16 * 128; i += 256) {
        int r = i >> 7, c = i & 127;
        int n = node0 + r;
        xs[i] = (n < NN) ? x[(long)n * 128 + c] : 0.f;
    }
    __syncthreads();
    const int ch = tid & 63;
    const int rbase = tid >> 6;      // 0..3
    float acc[4] = {0.f, 0.f, 0.f, 0.f};
    for (int k = 0; k < 128; ++k) {
        float w = ws[k * 64 + ch];
#pragma unroll
        for (int j = 0; j < 4; ++j)
            acc[j] += xs[(rbase + j * 4) * 128 + k] * w;
    }
#pragma unroll
    for (int j = 0; j < 4; ++j) {
        int n = node0 + rbase + j * 4;
        if (n < NN) h1[(long)n * 64 + ch] = acc[j];
    }
}

// ---------- alpha1: per (node, head) dot of h1 fragment with att vectors ----
__global__ __launch_bounds__(256) void alpha1_kernel(
        const float* __restrict__ h1, const float* __restrict__ att_s,
        const float* __restrict__ att_d,
        float* __restrict__ alpha_s, float* __restrict__ alpha_d) {
    int i = blockIdx.x * 256 + threadIdx.x;   // i = node*8 + head
    if (i >= NN * 8) return;
    int h = i & 7;
    const float* hp = h1 + (long)i * 8;       // (n*8+h)*8 == n*64 + h*8
    float s = 0.f, d = 0.f;
#pragma unroll
    for (int c = 0; c < 8; ++c) {
        float v = hp[c];
        s += v * att_s[h * 8 + c];
        d += v * att_d[h * 8 + c];
    }
    alpha_s[i] = s;
    alpha_d[i] = d;
}

// ---------- edge pass A: segment max over dst (8 heads) ----------
__global__ __launch_bounds__(256) void edge_max1(
        const int* __restrict__ ei, const float* __restrict__ as,
        const float* __restrict__ ad, unsigned* __restrict__ m1) {
    int e = blockIdx.x * 256 + threadIdx.x;
    if (e >= ET) return;
    int s, d;
    if (e < EE) { s = ei[e]; d = ei[EE + e]; } else { s = d = e - EE; }
#pragma unroll
    for (int h = 0; h < 8; ++h) {
        float v = leaky(as[s * 8 + h] + ad[d * 8 + h]);
        atomicMax(&m1[d * 8 + h], enc_f32(v));
    }
}

// ---------- edge pass B: exp-sum over dst ----------
__global__ __launch_bounds__(256) void edge_expsum1(
        const int* __restrict__ ei, const float* __restrict__ as,
        const float* __restrict__ ad, const unsigned* __restrict__ m1,
        float* __restrict__ den1) {
    int e = blockIdx.x * 256 + threadIdx.x;
    if (e >= ET) return;
    int s, d;
    if (e < EE) { s = ei[e]; d = ei[EE + e]; } else { s = d = e - EE; }
#pragma unroll
    for (int h = 0; h < 8; ++h) {
        float v = leaky(as[s * 8 + h] + ad[d * 8 + h]);
        float ex = __expf(v - dec_f32(m1[d * 8 + h]));
        atomicAdd(&den1[d * 8 + h], ex);
    }
}

// ---------- edge pass C: weighted scatter, 64 lanes per edge ----------
__global__ __launch_bounds__(256) void edge_scatter1(
        const int* __restrict__ ei, const float* __restrict__ as,
        const float* __restrict__ ad, const unsigned* __restrict__ m1,
        const float* __restrict__ den1, const float* __restrict__ h1,
        float* __restrict__ out1) {
    long gid = (long)blockIdx.x * 256 + threadIdx.x;
    long e = gid >> 6;
    int c = (int)(gid & 63);
    if (e >= ET) return;
    int s, d;
    if (e < EE) { s = ei[e]; d = ei[EE + e]; } else { s = d = (int)(e - EE); }
    int h = c >> 3;
    float v = leaky(as[s * 8 + h] + ad[d * 8 + h]);
    float ex = __expf(v - dec_f32(m1[d * 8 + h]));
    float alpha = ex / (den1[d * 8 + h] + 1e-16f);
    atomicAdd(&out1[(long)d * 64 + c], h1[(long)s * 64 + c] * alpha);
}

// ---------- GEMM2 + alpha2: h2[N,2] = relu(out1+b1) @ W2[64,2] ----------
__global__ __launch_bounds__(256) void gemm2_kernel(
        const float* __restrict__ out1, const float* __restrict__ b1,
        const float* __restrict__ W2, const float* __restrict__ as2,
        const float* __restrict__ ad2, float* __restrict__ h2,
        float* __restrict__ alpha_s2, float* __restrict__ alpha_d2) {
    int n = blockIdx.x * 256 + threadIdx.x;
    if (n >= NN) return;
    float a0 = 0.f, a1 = 0.f;
    for (int k = 0; k < 64; ++k) {
        float v = out1[(long)n * 64 + k] + b1[k];
        v = v > 0.f ? v : 0.f;
        a0 += v * W2[k * 2];
        a1 += v * W2[k * 2 + 1];
    }
    h2[n * 2] = a0;
    h2[n * 2 + 1] = a1;
    alpha_s2[n] = a0 * as2[0] + a1 * as2[1];
    alpha_d2[n] = a0 * ad2[0] + a1 * ad2[1];
}

// ---------- conv2 edge passes (1 head) ----------
__global__ __launch_bounds__(256) void edge_max2(
        const int* __restrict__ ei, const float* __restrict__ as,
        const float* __restrict__ ad, unsigned* __restrict__ m2) {
    int e = blockIdx.x * 256 + threadIdx.x;
    if (e >= ET) return;
    int s, d;
    if (e < EE) { s = ei[e]; d = ei[EE + e]; } else { s = d = e - EE; }
    float v = leaky(as[s] + ad[d]);
    atomicMax(&m2[d], enc_f32(v));
}

__global__ __launch_bounds__(256) void edge_expsum2(
        const int* __restrict__ ei, const float* __restrict__ as,
        const float* __restrict__ ad, const unsigned* __restrict__ m2,
        float* __restrict__ den2) {
    int e = blockIdx.x * 256 + threadIdx.x;
    if (e >= ET) return;
    int s, d;
    if (e < EE) { s = ei[e]; d = ei[EE + e]; } else { s = d = e - EE; }
    float v = leaky(as[s] + ad[d]);
    atomicAdd(&den2[d], __expf(v - dec_f32(m2[d])));
}

__global__ __launch_bounds__(256) void edge_scatter2(
        const int* __restrict__ ei, const float* __restrict__ as,
        const float* __restrict__ ad, const unsigned* __restrict__ m2,
        const float* __restrict__ den2, const float* __restrict__ h2,
        float* __restrict__ out2) {
    int e = blockIdx.x * 256 + threadIdx.x;
    if (e >= ET) return;
    int s, d;
    if (e < EE) { s = ei[e]; d = ei[EE + e]; } else { s = d = e - EE; }
    float v = leaky(as[s] + ad[d]);
    float ex = __expf(v - dec_f32(m2[d]));
    float alpha = ex / (den2[d] + 1e-16f);
    atomicAdd(&out2[d * 2], h2[s * 2] * alpha);
    atomicAdd(&out2[d * 2 + 1], h2[s * 2 + 1] * alpha);
}

// ---------- pooling: LDS partial sums per block, then global atomics -------
__global__ __launch_bounds__(256) void pool_kernel(
        const int* __restrict__ batch, const float* __restrict__ out2,
        float* __restrict__ pooled /*128 sums + 64 counts*/) {
    __shared__ float ls[192];
    int tid = threadIdx.x;
    if (tid < 192) ls[tid] = 0.f;
    __syncthreads();
    int n = blockIdx.x * 256 + tid;
    if (n < NN) {
        int g = batch[n];
        atomicAdd(&ls[g * 2], out2[n * 2]);
        atomicAdd(&ls[g * 2 + 1], out2[n * 2 + 1]);
        atomicAdd(&ls[128 + g], 1.f);
    }
    __syncthreads();
    if (tid < 192) atomicAdd(&pooled[tid], ls[tid]);
}

// ---------- finalize: mean, +b2, log_softmax ----------
__global__ __launch_bounds__(64) void final_kernel(
        const float* __restrict__ pooled, const float* __restrict__ b2,
        float* __restrict__ out) {
    int g = threadIdx.x;
    if (g >= 64) return;
    float c = pooled[128 + g];
    float denom = c > 1.f ? c : 1.f;
    float p0 = pooled[g * 2] / denom + b2[0];
    float p1 = pooled[g * 2 + 1] / denom + b2[1];
    float m = fmaxf(p0, p1);
    float lse = m + logf(expf(p0 - m) + expf(p1 - m));
    out[g * 2] = p0 - lse;
    out[g * 2 + 1] = p1 - lse;
}

extern "C" void kernel_launch(void* const* d_in, const int* in_sizes, int n_in,
                              void* d_out, int out_size, void* d_ws, size_t ws_size,
                              hipStream_t stream) {
    const float* x   = (const float*)d_in[0];
    const int*   ei  = (const int*)d_in[1];     // [2,E] int32
    const int*   bat = (const int*)d_in[2];     // [N]
    const float* W1  = (const float*)d_in[3];
    const float* as1 = (const float*)d_in[4];
    const float* ad1 = (const float*)d_in[5];
    const float* b1  = (const float*)d_in[6];
    const float* W2  = (const float*)d_in[7];
    const float* as2 = (const float*)d_in[8];
    const float* ad2 = (const float*)d_in[9];
    const float* b2  = (const float*)d_in[10];
    float* out = (float*)d_out;

    float* ws = (float*)d_ws;
    // workspace layout (element offsets)
    const long off_h1   = 0;                       // N*64
    const long off_as1  = off_h1  + (long)NN * 64; // N*8
    const long off_ad1  = off_as1 + (long)NN * 8;  // N*8
    const long off_zero = off_ad1 + (long)NN * 8;  // ---- zero region ----
    const long off_out1 = off_zero;                // N*64
    const long off_m1   = off_out1 + (long)NN * 64;// N*8 (uint)
    const long off_den1 = off_m1   + (long)NN * 8; // N*8
    const long off_m2   = off_den1 + (long)NN * 8; // N (uint)
    const long off_den2 = off_m2   + NN;           // N
    const long off_out2 = off_den2 + NN;           // N*2
    const long off_pool = off_out2 + (long)NN * 2; // 192
    const long zero_elems = off_pool + 192 - off_zero;
    const long off_h2   = off_pool + 192;          // N*2
    const long off_as2o = off_h2   + (long)NN * 2; // N
    const long off_ad2o = off_as2o + NN;           // N

    hipMemsetAsync(ws + off_zero, 0, zero_elems * sizeof(float), stream);

    gemm1_kernel<<<NN / 16, 256, 0, stream>>>(x, W1, ws + off_h1);
    alpha1_kernel<<<(NN * 8 + 255) / 256, 256, 0, stream>>>(
        ws + off_h1, as1, ad1, ws + off_as1, ws + off_ad1);

    const int eb = (ET + 255) / 256;
    edge_max1<<<eb, 256, 0, stream>>>(ei, ws + off_as1, ws + off_ad1,
                                      (unsigned*)(ws + off_m1));
    edge_expsum1<<<eb, 256, 0, stream>>>(ei, ws + off_as1, ws + off_ad1,
                                         (const unsigned*)(ws + off_m1),
                                         ws + off_den1);
    const long sc_threads = (long)ET * 64;
    edge_scatter1<<<(unsigned)((sc_threads + 255) / 256), 256, 0, stream>>>(
        ei, ws + off_as1, ws + off_ad1, (const unsigned*)(ws + off_m1),
        ws + off_den1, ws + off_h1, ws + off_out1);

    gemm2_kernel<<<(NN + 255) / 256, 256, 0, stream>>>(
        ws + off_out1, b1, W2, as2, ad2,
        ws + off_h2, ws + off_as2o, ws + off_ad2o);

    edge_max2<<<eb, 256, 0, stream>>>(ei, ws + off_as2o, ws + off_ad2o,
                                      (unsigned*)(ws + off_m2));
    edge_expsum2<<<eb, 256, 0, stream>>>(ei, ws + off_as2o, ws + off_ad2o,
                                         (const unsigned*)(ws + off_m2),
                                         ws + off_den2);
    edge_scatter2<<<eb, 256, 0, stream>>>(ei, ws + off_as2o, ws + off_ad2o,
                                          (const unsigned*)(ws + off_m2),
                                          ws + off_den2, ws + off_h2,
                                          ws + off_out2);

    pool_kernel<<<(NN + 255) / 256, 256, 0, stream>>>(
        bat, ws + off_out2, ws + off_pool);
    final_kernel<<<1, 64, 0, stream>>>(ws + off_pool, b2, out);
}

// Round 2
// 787.183 us; speedup vs baseline: 2.6473x; 2.6473x over previous
//
#include <hip/hip_runtime.h>
#include <hip/hip_bf16.h>
#include <math.h>

// Problem constants
#define NN 100000
#define EE 1600000
#define ET 1700000            // E + N self-loops
#define NEG_SLOPE 0.2f

__device__ __forceinline__ float leaky(float v) {
    return v > 0.f ? v : NEG_SLOPE * v;
}

// ---------- GEMM1: h1[N,64] = x[N,128] @ W1[128,64] ----------
__global__ __launch_bounds__(256) void gemm1_kernel(
        const float* __restrict__ x, const float* __restrict__ W1,
        float* __restrict__ h1) {
    __shared__ float ws[128 * 64];   // 32 KB
    __shared__ float xs[16 * 128];   // 8 KB
    const int tid = threadIdx.x;
    const int node0 = blockIdx.x * 16;
    for (int i = tid; i < 128 * 64; i += 256) ws[i] = W1[i];
    for (int i = tid; i < 16 * 128; i += 256) {
        int r = i >> 7, c = i & 127;
        int n = node0 + r;
        xs[i] = (n < NN) ? x[(long)n * 128 + c] : 0.f;
    }
    __syncthreads();
    const int ch = tid & 63;
    const int rbase = tid >> 6;      // 0..3
    float acc[4] = {0.f, 0.f, 0.f, 0.f};
    for (int k = 0; k < 128; ++k) {
        float w = ws[k * 64 + ch];
#pragma unroll
        for (int j = 0; j < 4; ++j)
            acc[j] += xs[(rbase + j * 4) * 128 + k] * w;
    }
#pragma unroll
    for (int j = 0; j < 4; ++j) {
        int n = node0 + rbase + j * 4;
        if (n < NN) h1[(long)n * 64 + ch] = acc[j];
    }
}

// ---------- alpha1: per (node, head) dots with att vectors ----------
__global__ __launch_bounds__(256) void alpha1_kernel(
        const float* __restrict__ h1, const float* __restrict__ att_s,
        const float* __restrict__ att_d,
        float* __restrict__ alpha_s, float* __restrict__ alpha_d) {
    int i = blockIdx.x * 256 + threadIdx.x;   // i = node*8 + head
    if (i >= NN * 8) return;
    int h = i & 7;
    const float* hp = h1 + (long)i * 8;
    float s = 0.f, d = 0.f;
#pragma unroll
    for (int c = 0; c < 8; ++c) {
        float v = hp[c];
        s += v * att_s[h * 8 + c];
        d += v * att_d[h * 8 + c];
    }
    alpha_s[i] = s;
    alpha_d[i] = d;
}

// ---------- CSR build: degree histogram ----------
__global__ __launch_bounds__(256) void deg_hist_kernel(
        const int* __restrict__ ei, int* __restrict__ deg) {
    int e = blockIdx.x * 256 + threadIdx.x;
    if (e >= ET) return;
    int d = (e < EE) ? ei[EE + e] : (e - EE);
    atomicAdd(&deg[d], 1);
}

// ---------- CSR build: single-block exclusive scan -> rowptr, cursor ------
__global__ __launch_bounds__(1024) void scan_kernel(
        const int* __restrict__ deg, int* __restrict__ rowptr,
        int* __restrict__ cursor) {
    __shared__ int lsum[1024];
    const int t = threadIdx.x;
    const int CH = (NN + 1023) / 1024;          // 98
    int lo = t * CH;
    int hi = lo + CH; if (hi > NN) hi = NN; if (lo > NN) lo = NN;
    int s = 0;
    for (int i = lo; i < hi; ++i) s += deg[i];
    lsum[t] = s;
    __syncthreads();
    for (int off = 1; off < 1024; off <<= 1) {
        int v = (t >= off) ? lsum[t - off] : 0;
        __syncthreads();
        lsum[t] += v;
        __syncthreads();
    }
    int run = (t == 0) ? 0 : lsum[t - 1];
    for (int i = lo; i < hi; ++i) {
        rowptr[i] = run; cursor[i] = run; run += deg[i];
    }
    if (t == 1023) rowptr[NN] = lsum[1023];
}

// ---------- CSR build: scatter fill ----------
__global__ __launch_bounds__(256) void csr_fill_kernel(
        const int* __restrict__ ei, int* __restrict__ cursor,
        int* __restrict__ csr_src) {
    int e = blockIdx.x * 256 + threadIdx.x;
    if (e >= ET) return;
    int s, d;
    if (e < EE) { s = ei[e]; d = ei[EE + e]; } else { s = d = e - EE; }
    int pos = atomicAdd(&cursor[d], 1);
    csr_src[pos] = s;
}

// ---------- conv1 fused: online softmax + aggregate + ReLU/bias + gemm2 ---
// One wave (64 lanes) per dst node; lane c = output channel, head h=c>>3.
__global__ __launch_bounds__(256) void conv1_fused_kernel(
        const int* __restrict__ rowptr, const int* __restrict__ csr_src,
        const float* __restrict__ as1, const float* __restrict__ ad1,
        const float* __restrict__ h1, const float* __restrict__ b1,
        const float* __restrict__ W2, const float* __restrict__ as2,
        const float* __restrict__ ad2,
        float* __restrict__ h2, float* __restrict__ as2o,
        float* __restrict__ ad2o) {
    long gid = (long)blockIdx.x * 256 + threadIdx.x;
    int n = (int)(gid >> 6);
    if (n >= NN) return;
    int c = threadIdx.x & 63;
    int h = c >> 3;
    float adh = ad1[n * 8 + h];
    int jb = rowptr[n], je = rowptr[n + 1];
    float m = -1e30f, l = 0.f, acc = 0.f;
    for (int j = jb; j < je; ++j) {
        int s = csr_src[j];
        float e = leaky(as1[s * 8 + h] + adh);
        float mn = fmaxf(m, e);
        float sc = __expf(m - mn);
        float p = __expf(e - mn);
        l = l * sc + p;
        acc = acc * sc + p * h1[(long)s * 64 + c];
        m = mn;
    }
    float o = acc / (l + 1e-16f);
    float a = o + b1[c];
    a = a > 0.f ? a : 0.f;                 // ReLU
    // fused gemm2: h2[n,j] = sum_c a_c * W2[c,j]
    float r0 = a * W2[c * 2];
    float r1 = a * W2[c * 2 + 1];
#pragma unroll
    for (int off = 32; off > 0; off >>= 1) {
        r0 += __shfl_xor(r0, off, 64);
        r1 += __shfl_xor(r1, off, 64);
    }
    if (c == 0) {
        h2[n * 2]     = r0;
        h2[n * 2 + 1] = r1;
        as2o[n] = r0 * as2[0] + r1 * as2[1];
        ad2o[n] = r0 * ad2[0] + r1 * ad2[1];
    }
}

// ---------- conv2 fused with mean-pool (LDS partials) ----------
__global__ __launch_bounds__(256) void conv2_pool_kernel(
        const int* __restrict__ rowptr, const int* __restrict__ csr_src,
        const float* __restrict__ as2o, const float* __restrict__ ad2o,
        const float* __restrict__ h2, const int* __restrict__ batch,
        float* __restrict__ pooled /*128 sums + 64 counts*/) {
    __shared__ float ls[192];
    int tid = threadIdx.x;
    if (tid < 192) ls[tid] = 0.f;
    __syncthreads();
    int n = blockIdx.x * 256 + tid;
    if (n < NN) {
        float adn = ad2o[n];
        int jb = rowptr[n], je = rowptr[n + 1];
        float m = -1e30f, l = 0.f, a0 = 0.f, a1 = 0.f;
        for (int j = jb; j < je; ++j) {
            int s = csr_src[j];
            float e = leaky(as2o[s] + adn);
            float mn = fmaxf(m, e);
            float sc = __expf(m - mn);
            float p = __expf(e - mn);
            l = l * sc + p;
            a0 = a0 * sc + p * h2[s * 2];
            a1 = a1 * sc + p * h2[s * 2 + 1];
            m = mn;
        }
        float inv = 1.f / (l + 1e-16f);
        int g = batch[n];
        atomicAdd(&ls[g * 2],     a0 * inv);
        atomicAdd(&ls[g * 2 + 1], a1 * inv);
        atomicAdd(&ls[128 + g],   1.f);
    }
    __syncthreads();
    if (tid < 192) atomicAdd(&pooled[tid], ls[tid]);
}

// ---------- finalize: mean, +b2, log_softmax ----------
__global__ __launch_bounds__(64) void final_kernel(
        const float* __restrict__ pooled, const float* __restrict__ b2,
        float* __restrict__ out) {
    int g = threadIdx.x;
    if (g >= 64) return;
    float c = pooled[128 + g];
    float denom = c > 1.f ? c : 1.f;
    float p0 = pooled[g * 2] / denom + b2[0];
    float p1 = pooled[g * 2 + 1] / denom + b2[1];
    float m = fmaxf(p0, p1);
    float lse = m + logf(expf(p0 - m) + expf(p1 - m));
    out[g * 2] = p0 - lse;
    out[g * 2 + 1] = p1 - lse;
}

extern "C" void kernel_launch(void* const* d_in, const int* in_sizes, int n_in,
                              void* d_out, int out_size, void* d_ws, size_t ws_size,
                              hipStream_t stream) {
    const float* x   = (const float*)d_in[0];
    const int*   ei  = (const int*)d_in[1];     // [2,E] int32
    const int*   bat = (const int*)d_in[2];     // [N]
    const float* W1  = (const float*)d_in[3];
    const float* as1 = (const float*)d_in[4];
    const float* ad1 = (const float*)d_in[5];
    const float* b1  = (const float*)d_in[6];
    const float* W2  = (const float*)d_in[7];
    const float* as2 = (const float*)d_in[8];
    const float* ad2 = (const float*)d_in[9];
    const float* b2  = (const float*)d_in[10];
    float* out = (float*)d_out;

    float* ws = (float*)d_ws;
    // workspace layout (element offsets)
    const long off_h1     = 0;                          // N*64
    const long off_as1    = off_h1   + (long)NN * 64;   // N*8
    const long off_ad1    = off_as1  + (long)NN * 8;    // N*8
    const long off_h2     = off_ad1  + (long)NN * 8;    // N*2
    const long off_as2o   = off_h2   + (long)NN * 2;    // N
    const long off_ad2o   = off_as2o + NN;              // N
    const long off_rowptr = off_ad2o + NN;              // N+1 (int)
    const long off_cursor = off_rowptr + NN + 1;        // N   (int)
    const long off_csr    = off_cursor + NN;            // ET  (int)
    const long off_zero   = off_csr + ET;               // ---- zeroed ----
    const long off_deg    = off_zero;                   // N   (int)
    const long off_pool   = off_deg + NN;               // 192
    const long zero_elems = off_pool + 192 - off_zero;

    hipMemsetAsync(ws + off_zero, 0, zero_elems * sizeof(float), stream);

    gemm1_kernel<<<NN / 16, 256, 0, stream>>>(x, W1, ws + off_h1);
    alpha1_kernel<<<(NN * 8 + 255) / 256, 256, 0, stream>>>(
        ws + off_h1, as1, ad1, ws + off_as1, ws + off_ad1);

    const int eb = (ET + 255) / 256;
    deg_hist_kernel<<<eb, 256, 0, stream>>>(ei, (int*)(ws + off_deg));
    scan_kernel<<<1, 1024, 0, stream>>>((const int*)(ws + off_deg),
                                        (int*)(ws + off_rowptr),
                                        (int*)(ws + off_cursor));
    csr_fill_kernel<<<eb, 256, 0, stream>>>(ei, (int*)(ws + off_cursor),
                                            (int*)(ws + off_csr));

    conv1_fused_kernel<<<(int)(((long)NN * 64 + 255) / 256), 256, 0, stream>>>(
        (const int*)(ws + off_rowptr), (const int*)(ws + off_csr),
        ws + off_as1, ws + off_ad1, ws + off_h1, b1, W2, as2, ad2,
        ws + off_h2, ws + off_as2o, ws + off_ad2o);

    conv2_pool_kernel<<<(NN + 255) / 256, 256, 0, stream>>>(
        (const int*)(ws + off_rowptr), (const int*)(ws + off_csr),
        ws + off_as2o, ws + off_ad2o, ws + off_h2, bat, ws + off_pool);

    final_kernel<<<1, 64, 0, stream>>>(ws + off_pool, b2, out);
}

// Round 3
// 574.537 us; speedup vs baseline: 3.6271x; 1.3701x over previous
//
#include <hip/hip_runtime.h>
#include <hip/hip_bf16.h>
#include <math.h>

// Problem constants
#define NN 100000
#define EE 1600000
#define ET 1700000            // E + N self-loops
#define NEG_SLOPE 0.2f
#define SCAN_NB 392           // 392*256 = 100352 >= NN

__device__ __forceinline__ float leaky(float v) {
    return v > 0.f ? v : NEG_SLOPE * v;
}

// ---------- GEMM1: h1[N,64] = x[N,128] @ W1[128,64] ----------
__global__ __launch_bounds__(256) void gemm1_kernel(
        const float* __restrict__ x, const float* __restrict__ W1,
        float* __restrict__ h1) {
    __shared__ float ws[128 * 64];   // 32 KB
    __shared__ float xs[16 * 128];   // 8 KB
    const int tid = threadIdx.x;
    const int node0 = blockIdx.x * 16;
    for (int i = tid; i < 128 * 64; i += 256) ws[i] = W1[i];
    for (int i = tid; i < 16 * 128; i += 256) {
        int r = i >> 7, c = i & 127;
        int n = node0 + r;
        xs[i] = (n < NN) ? x[(long)n * 128 + c] : 0.f;
    }
    __syncthreads();
    const int ch = tid & 63;
    const int rbase = tid >> 6;      // 0..3
    float acc[4] = {0.f, 0.f, 0.f, 0.f};
    for (int k = 0; k < 128; ++k) {
        float w = ws[k * 64 + ch];
#pragma unroll
        for (int j = 0; j < 4; ++j)
            acc[j] += xs[(rbase + j * 4) * 128 + k] * w;
    }
#pragma unroll
    for (int j = 0; j < 4; ++j) {
        int n = node0 + rbase + j * 4;
        if (n < NN) h1[(long)n * 64 + ch] = acc[j];
    }
}

// ---------- alpha1: per (node, head) dots with att vectors ----------
__global__ __launch_bounds__(256) void alpha1_kernel(
        const float* __restrict__ h1, const float* __restrict__ att_s,
        const float* __restrict__ att_d,
        float* __restrict__ alpha_s, float* __restrict__ alpha_d) {
    int i = blockIdx.x * 256 + threadIdx.x;   // i = node*8 + head
    if (i >= NN * 8) return;
    int h = i & 7;
    const float* hp = h1 + (long)i * 8;
    float s = 0.f, d = 0.f;
#pragma unroll
    for (int c = 0; c < 8; ++c) {
        float v = hp[c];
        s += v * att_s[h * 8 + c];
        d += v * att_d[h * 8 + c];
    }
    alpha_s[i] = s;
    alpha_d[i] = d;
}

// ---------- CSR build: degree histogram ----------
__global__ __launch_bounds__(256) void deg_hist_kernel(
        const int* __restrict__ ei, int* __restrict__ deg) {
    int e = blockIdx.x * 256 + threadIdx.x;
    if (e >= ET) return;
    int d = (e < EE) ? ei[EE + e] : (e - EE);
    atomicAdd(&deg[d], 1);
}

// ---------- hierarchical scan phase 1: per-block sums ----------
__global__ __launch_bounds__(256) void scan_phase1(
        const int* __restrict__ deg, int* __restrict__ blocksum) {
    __shared__ int sh[256];
    int t = threadIdx.x;
    int i = blockIdx.x * 256 + t;
    sh[t] = (i < NN) ? deg[i] : 0;
    __syncthreads();
    for (int off = 128; off > 0; off >>= 1) {
        if (t < off) sh[t] += sh[t + off];
        __syncthreads();
    }
    if (t == 0) blocksum[blockIdx.x] = sh[0];
}

// ---------- phase 2: exclusive scan of 392 block sums (1 block) ----------
__global__ __launch_bounds__(512) void scan_phase2(
        const int* __restrict__ blocksum, int* __restrict__ blockoff) {
    __shared__ int sh[512];
    int t = threadIdx.x;
    int v = (t < SCAN_NB) ? blocksum[t] : 0;
    sh[t] = v;
    __syncthreads();
    for (int off = 1; off < 512; off <<= 1) {
        int u = (t >= off) ? sh[t - off] : 0;
        __syncthreads();
        sh[t] += u;
        __syncthreads();
    }
    if (t < SCAN_NB) blockoff[t] = sh[t] - v;   // exclusive
}

// ---------- phase 3: intra-block exclusive scan + offset -> rowptr/cursor --
__global__ __launch_bounds__(256) void scan_phase3(
        const int* __restrict__ deg, const int* __restrict__ blockoff,
        int* __restrict__ rowptr, int* __restrict__ cursor) {
    __shared__ int sh[256];
    int t = threadIdx.x;
    int i = blockIdx.x * 256 + t;
    int d = (i < NN) ? deg[i] : 0;
    sh[t] = d;
    __syncthreads();
    for (int off = 1; off < 256; off <<= 1) {
        int u = (t >= off) ? sh[t - off] : 0;
        __syncthreads();
        sh[t] += u;
        __syncthreads();
    }
    if (i < NN) {
        int excl = blockoff[blockIdx.x] + sh[t] - d;
        rowptr[i] = excl;
        cursor[i] = excl;
        if (i == NN - 1) rowptr[NN] = excl + d;
    }
}

// ---------- CSR build: scatter fill ----------
__global__ __launch_bounds__(256) void csr_fill_kernel(
        const int* __restrict__ ei, int* __restrict__ cursor,
        int* __restrict__ csr_src) {
    int e = blockIdx.x * 256 + threadIdx.x;
    if (e >= ET) return;
    int s, d;
    if (e < EE) { s = ei[e]; d = ei[EE + e]; } else { s = d = e - EE; }
    int pos = atomicAdd(&cursor[d], 1);
    csr_src[pos] = s;
}

// ---------- conv1 fused: online softmax + aggregate + ReLU/bias + gemm2 ---
// One wave (64 lanes) per dst node; lane c = output channel, head h=c>>3.
__global__ __launch_bounds__(256) void conv1_fused_kernel(
        const int* __restrict__ rowptr, const int* __restrict__ csr_src,
        const float* __restrict__ as1, const float* __restrict__ ad1,
        const float* __restrict__ h1, const float* __restrict__ b1,
        const float* __restrict__ W2, const float* __restrict__ as2,
        const float* __restrict__ ad2,
        float* __restrict__ h2, float* __restrict__ as2o,
        float* __restrict__ ad2o) {
    long gid = (long)blockIdx.x * 256 + threadIdx.x;
    int n = (int)(gid >> 6);
    if (n >= NN) return;
    int c = threadIdx.x & 63;
    int h = c >> 3;
    float adh = ad1[n * 8 + h];
    int jb = rowptr[n], je = rowptr[n + 1];
    float m = -1e30f, l = 0.f, acc = 0.f;
    for (int j = jb; j < je; ++j) {
        int s = csr_src[j];
        float e = leaky(as1[s * 8 + h] + adh);
        float mn = fmaxf(m, e);
        float sc = __expf(m - mn);
        float p = __expf(e - mn);
        l = l * sc + p;
        acc = acc * sc + p * h1[(long)s * 64 + c];
        m = mn;
    }
    float o = acc / (l + 1e-16f);
    float a = o + b1[c];
    a = a > 0.f ? a : 0.f;                 // ReLU
    // fused gemm2: h2[n,j] = sum_c a_c * W2[c,j]
    float r0 = a * W2[c * 2];
    float r1 = a * W2[c * 2 + 1];
#pragma unroll
    for (int off = 32; off > 0; off >>= 1) {
        r0 += __shfl_xor(r0, off, 64);
        r1 += __shfl_xor(r1, off, 64);
    }
    if (c == 0) {
        h2[n * 2]     = r0;
        h2[n * 2 + 1] = r1;
        as2o[n] = r0 * as2[0] + r1 * as2[1];
        ad2o[n] = r0 * ad2[0] + r1 * ad2[1];
    }
}

// ---------- conv2 fused with mean-pool (LDS partials) ----------
__global__ __launch_bounds__(256) void conv2_pool_kernel(
        const int* __restrict__ rowptr, const int* __restrict__ csr_src,
        const float* __restrict__ as2o, const float* __restrict__ ad2o,
        const float* __restrict__ h2, const int* __restrict__ batch,
        float* __restrict__ pooled /*128 sums + 64 counts*/) {
    __shared__ float ls[192];
    int tid = threadIdx.x;
    if (tid < 192) ls[tid] = 0.f;
    __syncthreads();
    int n = blockIdx.x * 256 + tid;
    if (n < NN) {
        float adn = ad2o[n];
        int jb = rowptr[n], je = rowptr[n + 1];
        float m = -1e30f, l = 0.f, a0 = 0.f, a1 = 0.f;
        for (int j = jb; j < je; ++j) {
            int s = csr_src[j];
            float e = leaky(as2o[s] + adn);
            float mn = fmaxf(m, e);
            float sc = __expf(m - mn);
            float p = __expf(e - mn);
            l = l * sc + p;
            a0 = a0 * sc + p * h2[s * 2];
            a1 = a1 * sc + p * h2[s * 2 + 1];
            m = mn;
        }
        float inv = 1.f / (l + 1e-16f);
        int g = batch[n];
        atomicAdd(&ls[g * 2],     a0 * inv);
        atomicAdd(&ls[g * 2 + 1], a1 * inv);
        atomicAdd(&ls[128 + g],   1.f);
    }
    __syncthreads();
    if (tid < 192) atomicAdd(&pooled[tid], ls[tid]);
}

// ---------- finalize: mean, +b2, log_softmax ----------
__global__ __launch_bounds__(64) void final_kernel(
        const float* __restrict__ pooled, const float* __restrict__ b2,
        float* __restrict__ out) {
    int g = threadIdx.x;
    if (g >= 64) return;
    float c = pooled[128 + g];
    float denom = c > 1.f ? c : 1.f;
    float p0 = pooled[g * 2] / denom + b2[0];
    float p1 = pooled[g * 2 + 1] / denom + b2[1];
    float m = fmaxf(p0, p1);
    float lse = m + logf(expf(p0 - m) + expf(p1 - m));
    out[g * 2] = p0 - lse;
    out[g * 2 + 1] = p1 - lse;
}

extern "C" void kernel_launch(void* const* d_in, const int* in_sizes, int n_in,
                              void* d_out, int out_size, void* d_ws, size_t ws_size,
                              hipStream_t stream) {
    const float* x   = (const float*)d_in[0];
    const int*   ei  = (const int*)d_in[1];     // [2,E] int32
    const int*   bat = (const int*)d_in[2];     // [N]
    const float* W1  = (const float*)d_in[3];
    const float* as1 = (const float*)d_in[4];
    const float* ad1 = (const float*)d_in[5];
    const float* b1  = (const float*)d_in[6];
    const float* W2  = (const float*)d_in[7];
    const float* as2 = (const float*)d_in[8];
    const float* ad2 = (const float*)d_in[9];
    const float* b2  = (const float*)d_in[10];
    float* out = (float*)d_out;

    float* ws = (float*)d_ws;
    // workspace layout (element offsets)
    const long off_h1     = 0;                          // N*64
    const long off_as1    = off_h1   + (long)NN * 64;   // N*8
    const long off_ad1    = off_as1  + (long)NN * 8;    // N*8
    const long off_h2     = off_ad1  + (long)NN * 8;    // N*2
    const long off_as2o   = off_h2   + (long)NN * 2;    // N
    const long off_ad2o   = off_as2o + NN;              // N
    const long off_rowptr = off_ad2o + NN;              // N+1 (int)
    const long off_cursor = off_rowptr + NN + 1;        // N   (int)
    const long off_csr    = off_cursor + NN;            // ET  (int)
    const long off_bsum   = off_csr + ET;               // SCAN_NB (int)
    const long off_boff   = off_bsum + SCAN_NB;         // SCAN_NB (int)
    const long off_zero   = off_boff + SCAN_NB;         // ---- zeroed ----
    const long off_deg    = off_zero;                   // N   (int)
    const long off_pool   = off_deg + NN;               // 192
    const long zero_elems = off_pool + 192 - off_zero;

    hipMemsetAsync(ws + off_zero, 0, zero_elems * sizeof(float), stream);

    gemm1_kernel<<<NN / 16, 256, 0, stream>>>(x, W1, ws + off_h1);
    alpha1_kernel<<<(NN * 8 + 255) / 256, 256, 0, stream>>>(
        ws + off_h1, as1, ad1, ws + off_as1, ws + off_ad1);

    const int eb = (ET + 255) / 256;
    deg_hist_kernel<<<eb, 256, 0, stream>>>(ei, (int*)(ws + off_deg));
    scan_phase1<<<SCAN_NB, 256, 0, stream>>>((const int*)(ws + off_deg),
                                             (int*)(ws + off_bsum));
    scan_phase2<<<1, 512, 0, stream>>>((const int*)(ws + off_bsum),
                                       (int*)(ws + off_boff));
    scan_phase3<<<SCAN_NB, 256, 0, stream>>>((const int*)(ws + off_deg),
                                             (const int*)(ws + off_boff),
                                             (int*)(ws + off_rowptr),
                                             (int*)(ws + off_cursor));
    csr_fill_kernel<<<eb, 256, 0, stream>>>(ei, (int*)(ws + off_cursor),
                                            (int*)(ws + off_csr));

    conv1_fused_kernel<<<(int)(((long)NN * 64 + 255) / 256), 256, 0, stream>>>(
        (const int*)(ws + off_rowptr), (const int*)(ws + off_csr),
        ws + off_as1, ws + off_ad1, ws + off_h1, b1, W2, as2, ad2,
        ws + off_h2, ws + off_as2o, ws + off_ad2o);

    conv2_pool_kernel<<<(NN + 255) / 256, 256, 0, stream>>>(
        (const int*)(ws + off_rowptr), (const int*)(ws + off_csr),
        ws + off_as2o, ws + off_ad2o, ws + off_h2, bat, ws + off_pool);

    final_kernel<<<1, 64, 0, stream>>>(ws + off_pool, b2, out);
}

// Round 4
// 468.228 us; speedup vs baseline: 4.4506x; 1.2270x over previous
//
#include <hip/hip_runtime.h>
#include <hip/hip_bf16.h>
#include <math.h>

// Problem constants
#define NN 100000
#define EE 1600000
#define ET 1700000            // E + N self-loops
#define NEG_SLOPE 0.2f
#define SCAN_NB 392           // 392*256 = 100352 >= NN

__device__ __forceinline__ float leaky(float v) {
    return v > 0.f ? v : NEG_SLOPE * v;
}

// ---------- GEMM1 + fused alpha1 ----------
// h1[N,64] = x[N,128] @ W1[128,64]; alpha_s/d[n,h] = dot(h1[n,h*8:+8], att[h])
__global__ __launch_bounds__(256) void gemm1_kernel(
        const float* __restrict__ x, const float* __restrict__ W1,
        const float* __restrict__ att_s, const float* __restrict__ att_d,
        float* __restrict__ h1, float* __restrict__ alpha_s,
        float* __restrict__ alpha_d) {
    __shared__ float ws[128 * 64];   // 32 KB
    __shared__ float xs[16 * 128];   // 8 KB
    const int tid = threadIdx.x;
    const int node0 = blockIdx.x * 16;
    for (int i = tid; i < 128 * 64; i += 256) ws[i] = W1[i];
    for (int i = tid; i < 16 * 128; i += 256) {
        int r = i >> 7, c = i & 127;
        int n = node0 + r;
        xs[i] = (n < NN) ? x[(long)n * 128 + c] : 0.f;
    }
    __syncthreads();
    const int ch = tid & 63;
    const int rbase = tid >> 6;      // wave id; wave owns nodes rbase+{0,4,8,12}
    float acc[4] = {0.f, 0.f, 0.f, 0.f};
    for (int k = 0; k < 128; ++k) {
        float w = ws[k * 64 + ch];
#pragma unroll
        for (int j = 0; j < 4; ++j)
            acc[j] += xs[(rbase + j * 4) * 128 + k] * w;
    }
    float ats = att_s[ch], atd = att_d[ch];
#pragma unroll
    for (int j = 0; j < 4; ++j) {
        int n = node0 + rbase + j * 4;
        h1[(long)n * 64 + ch] = acc[j];
        float vs = acc[j] * ats;
        float vd = acc[j] * atd;
#pragma unroll
        for (int off = 1; off < 8; off <<= 1) {
            vs += __shfl_xor(vs, off, 64);
            vd += __shfl_xor(vd, off, 64);
        }
        if ((ch & 7) == 0) {
            alpha_s[n * 8 + (ch >> 3)] = vs;
            alpha_d[n * 8 + (ch >> 3)] = vd;
        }
    }
}

// ---------- CSR build: degree histogram ----------
__global__ __launch_bounds__(256) void deg_hist_kernel(
        const int* __restrict__ ei, int* __restrict__ deg) {
    int e = blockIdx.x * 256 + threadIdx.x;
    if (e >= ET) return;
    int d = (e < EE) ? ei[EE + e] : (e - EE);
    atomicAdd(&deg[d], 1);
}

// ---------- hierarchical scan phase 1: per-block sums ----------
__global__ __launch_bounds__(256) void scan_phase1(
        const int* __restrict__ deg, int* __restrict__ blocksum) {
    __shared__ int sh[256];
    int t = threadIdx.x;
    int i = blockIdx.x * 256 + t;
    sh[t] = (i < NN) ? deg[i] : 0;
    __syncthreads();
    for (int off = 128; off > 0; off >>= 1) {
        if (t < off) sh[t] += sh[t + off];
        __syncthreads();
    }
    if (t == 0) blocksum[blockIdx.x] = sh[0];
}

// ---------- phase 2: exclusive scan of block sums (1 block) ----------
__global__ __launch_bounds__(512) void scan_phase2(
        const int* __restrict__ blocksum, int* __restrict__ blockoff) {
    __shared__ int sh[512];
    int t = threadIdx.x;
    int v = (t < SCAN_NB) ? blocksum[t] : 0;
    sh[t] = v;
    __syncthreads();
    for (int off = 1; off < 512; off <<= 1) {
        int u = (t >= off) ? sh[t - off] : 0;
        __syncthreads();
        sh[t] += u;
        __syncthreads();
    }
    if (t < SCAN_NB) blockoff[t] = sh[t] - v;   // exclusive
}

// ---------- phase 3: intra-block exclusive scan + offset ----------
__global__ __launch_bounds__(256) void scan_phase3(
        const int* __restrict__ deg, const int* __restrict__ blockoff,
        int* __restrict__ rowptr, int* __restrict__ cursor) {
    __shared__ int sh[256];
    int t = threadIdx.x;
    int i = blockIdx.x * 256 + t;
    int d = (i < NN) ? deg[i] : 0;
    sh[t] = d;
    __syncthreads();
    for (int off = 1; off < 256; off <<= 1) {
        int u = (t >= off) ? sh[t - off] : 0;
        __syncthreads();
        sh[t] += u;
        __syncthreads();
    }
    if (i < NN) {
        int excl = blockoff[blockIdx.x] + sh[t] - d;
        rowptr[i] = excl;
        cursor[i] = excl;
        if (i == NN - 1) rowptr[NN] = excl + d;
    }
}

// ---------- CSR build: scatter fill ----------
__global__ __launch_bounds__(256) void csr_fill_kernel(
        const int* __restrict__ ei, int* __restrict__ cursor,
        int* __restrict__ csr_src) {
    int e = blockIdx.x * 256 + threadIdx.x;
    if (e >= ET) return;
    int s, d;
    if (e < EE) { s = ei[e]; d = ei[EE + e]; } else { s = d = e - EE; }
    int pos = atomicAdd(&cursor[d], 1);
    csr_src[pos] = s;
}

// ---------- conv1 fused: softmax-agg + ReLU/bias + gemm2 + rec pack ------
// One wave per dst node; lane c = channel, head h=c>>3. No-max softmax
// (logits are 0.1-scale; exp(e)/sum(exp(e)) == reference exactly in math).
__global__ __launch_bounds__(256) void conv1_fused_kernel(
        const int* __restrict__ rowptr, const int* __restrict__ csr_src,
        const float* __restrict__ as1, const float* __restrict__ ad1,
        const float* __restrict__ h1, const float* __restrict__ b1,
        const float* __restrict__ W2, const float* __restrict__ as2,
        const float* __restrict__ ad2, float4* __restrict__ rec) {
    long gid = (long)blockIdx.x * 256 + threadIdx.x;
    int n = (int)(gid >> 6);
    if (n >= NN) return;
    n = __builtin_amdgcn_readfirstlane(n);   // wave-uniform -> scalar loads
    int c = threadIdx.x & 63;
    int h = c >> 3;
    float adh = ad1[n * 8 + h];
    int jb = rowptr[n], je = rowptr[n + 1];
    float l0 = 0.f, l1 = 0.f, l2 = 0.f, l3 = 0.f;
    float a0 = 0.f, a1 = 0.f, a2 = 0.f, a3 = 0.f;
    int j = jb;
    for (; j + 3 < je; j += 4) {
        int s0 = csr_src[j], s1 = csr_src[j + 1];
        int s2 = csr_src[j + 2], s3 = csr_src[j + 3];
        float p0 = __expf(leaky(as1[s0 * 8 + h] + adh));
        float p1 = __expf(leaky(as1[s1 * 8 + h] + adh));
        float p2 = __expf(leaky(as1[s2 * 8 + h] + adh));
        float p3 = __expf(leaky(as1[s3 * 8 + h] + adh));
        l0 += p0; l1 += p1; l2 += p2; l3 += p3;
        a0 += p0 * h1[(long)s0 * 64 + c];
        a1 += p1 * h1[(long)s1 * 64 + c];
        a2 += p2 * h1[(long)s2 * 64 + c];
        a3 += p3 * h1[(long)s3 * 64 + c];
    }
    for (; j < je; ++j) {
        int s = csr_src[j];
        float p = __expf(leaky(as1[s * 8 + h] + adh));
        l0 += p;
        a0 += p * h1[(long)s * 64 + c];
    }
    float l = (l0 + l1) + (l2 + l3);
    float acc = (a0 + a1) + (a2 + a3);
    float o = acc / (l + 1e-16f);
    float a = o + b1[c];
    a = a > 0.f ? a : 0.f;                 // ReLU
    // fused gemm2: h2[n,j] = sum_c a_c * W2[c,j]
    float r0 = a * W2[c * 2];
    float r1 = a * W2[c * 2 + 1];
#pragma unroll
    for (int off = 32; off > 0; off >>= 1) {
        r0 += __shfl_xor(r0, off, 64);
        r1 += __shfl_xor(r1, off, 64);
    }
    if (c == 0) {
        float s2v = r0 * as2[0] + r1 * as2[1];
        float d2v = r0 * ad2[0] + r1 * ad2[1];
        rec[n] = make_float4(s2v, r0, r1, d2v);   // (as2o, h2_0, h2_1, ad2o)
    }
}

// ---------- conv2 fused with mean-pool (LDS partials) ----------
__global__ __launch_bounds__(256) void conv2_pool_kernel(
        const int* __restrict__ rowptr, const int* __restrict__ csr_src,
        const float4* __restrict__ rec, const int* __restrict__ batch,
        float* __restrict__ pooled /*128 sums + 64 counts*/) {
    __shared__ float ls[192];
    int tid = threadIdx.x;
    if (tid < 192) ls[tid] = 0.f;
    __syncthreads();
    int n = blockIdx.x * 256 + tid;
    if (n < NN) {
        float adn = rec[n].w;
        int jb = rowptr[n], je = rowptr[n + 1];
        float l0 = 0.f, l1 = 0.f, x0 = 0.f, x1 = 0.f, y0 = 0.f, y1 = 0.f;
        int j = jb;
        for (; j + 1 < je; j += 2) {
            float4 ra = rec[csr_src[j]];
            float4 rb = rec[csr_src[j + 1]];
            float pa = __expf(leaky(ra.x + adn));
            float pb = __expf(leaky(rb.x + adn));
            l0 += pa; x0 += pa * ra.y; y0 += pa * ra.z;
            l1 += pb; x1 += pb * rb.y; y1 += pb * rb.z;
        }
        for (; j < je; ++j) {
            float4 ra = rec[csr_src[j]];
            float pa = __expf(leaky(ra.x + adn));
            l0 += pa; x0 += pa * ra.y; y0 += pa * ra.z;
        }
        float inv = 1.f / (l0 + l1 + 1e-16f);
        int g = batch[n];
        atomicAdd(&ls[g * 2],     (x0 + x1) * inv);
        atomicAdd(&ls[g * 2 + 1], (y0 + y1) * inv);
        atomicAdd(&ls[128 + g],   1.f);
    }
    __syncthreads();
    if (tid < 192) atomicAdd(&pooled[tid], ls[tid]);
}

// ---------- finalize: mean, +b2, log_softmax ----------
__global__ __launch_bounds__(64) void final_kernel(
        const float* __restrict__ pooled, const float* __restrict__ b2,
        float* __restrict__ out) {
    int g = threadIdx.x;
    if (g >= 64) return;
    float c = pooled[128 + g];
    float denom = c > 1.f ? c : 1.f;
    float p0 = pooled[g * 2] / denom + b2[0];
    float p1 = pooled[g * 2 + 1] / denom + b2[1];
    float m = fmaxf(p0, p1);
    float lse = m + logf(expf(p0 - m) + expf(p1 - m));
    out[g * 2] = p0 - lse;
    out[g * 2 + 1] = p1 - lse;
}

extern "C" void kernel_launch(void* const* d_in, const int* in_sizes, int n_in,
                              void* d_out, int out_size, void* d_ws, size_t ws_size,
                              hipStream_t stream) {
    const float* x   = (const float*)d_in[0];
    const int*   ei  = (const int*)d_in[1];     // [2,E] int32
    const int*   bat = (const int*)d_in[2];     // [N]
    const float* W1  = (const float*)d_in[3];
    const float* as1 = (const float*)d_in[4];
    const float* ad1 = (const float*)d_in[5];
    const float* b1  = (const float*)d_in[6];
    const float* W2  = (const float*)d_in[7];
    const float* as2 = (const float*)d_in[8];
    const float* ad2 = (const float*)d_in[9];
    const float* b2  = (const float*)d_in[10];
    float* out = (float*)d_out;

    float* ws = (float*)d_ws;
    // workspace layout (element offsets; off_rec 16B-aligned)
    const long off_h1     = 0;                          // N*64
    const long off_as1    = off_h1   + (long)NN * 64;   // N*8
    const long off_ad1    = off_as1  + (long)NN * 8;    // N*8
    const long off_rec    = off_ad1  + (long)NN * 8;    // N*4 (float4)
    const long off_rowptr = off_rec  + (long)NN * 4;    // N+1 (int)
    const long off_cursor = off_rowptr + NN + 1;        // N   (int)
    const long off_csr    = off_cursor + NN;            // ET  (int)
    const long off_bsum   = off_csr + ET;               // SCAN_NB (int)
    const long off_boff   = off_bsum + SCAN_NB;         // SCAN_NB (int)
    const long off_zero   = off_boff + SCAN_NB;         // ---- zeroed ----
    const long off_deg    = off_zero;                   // N   (int)
    const long off_pool   = off_deg + NN;               // 192
    const long zero_elems = off_pool + 192 - off_zero;

    hipMemsetAsync(ws + off_zero, 0, zero_elems * sizeof(float), stream);

    gemm1_kernel<<<NN / 16, 256, 0, stream>>>(
        x, W1, as1, ad1, ws + off_h1, ws + off_as1, ws + off_ad1);

    const int eb = (ET + 255) / 256;
    deg_hist_kernel<<<eb, 256, 0, stream>>>(ei, (int*)(ws + off_deg));
    scan_phase1<<<SCAN_NB, 256, 0, stream>>>((const int*)(ws + off_deg),
                                             (int*)(ws + off_bsum));
    scan_phase2<<<1, 512, 0, stream>>>((const int*)(ws + off_bsum),
                                       (int*)(ws + off_boff));
    scan_phase3<<<SCAN_NB, 256, 0, stream>>>((const int*)(ws + off_deg),
                                             (const int*)(ws + off_boff),
                                             (int*)(ws + off_rowptr),
                                             (int*)(ws + off_cursor));
    csr_fill_kernel<<<eb, 256, 0, stream>>>(ei, (int*)(ws + off_cursor),
                                            (int*)(ws + off_csr));

    conv1_fused_kernel<<<(int)(((long)NN * 64 + 255) / 256), 256, 0, stream>>>(
        (const int*)(ws + off_rowptr), (const int*)(ws + off_csr),
        ws + off_as1, ws + off_ad1, ws + off_h1, b1, W2, as2, ad2,
        (float4*)(ws + off_rec));

    conv2_pool_kernel<<<(NN + 255) / 256, 256, 0, stream>>>(
        (const int*)(ws + off_rowptr), (const int*)(ws + off_csr),
        (const float4*)(ws + off_rec), bat, ws + off_pool);

    final_kernel<<<1, 64, 0, stream>>>(ws + off_pool, b2, out);
}

// Round 5
// 401.221 us; speedup vs baseline: 5.1938x; 1.1670x over previous
//
#include <hip/hip_runtime.h>
#include <hip/hip_bf16.h>
#include <hip/hip_fp16.h>
#include <math.h>

// Problem constants
#define NN 100000
#define EE 1600000
#define ET 1700000            // E + N self-loops
#define NEG_SLOPE 0.2f
#define SCAN_NB 392           // 392*256 = 100352 >= NN
#define NRANGE 8
#define RSIZE 12500           // NN / NRANGE
#define EPT 8                 // edges per thread in range kernels
#define CHUNK (256 * EPT)     // 2048 edges per block
#define NCHUNK ((ET + CHUNK - 1) / CHUNK)

__device__ __forceinline__ float leaky(float v) {
    return v > 0.f ? v : NEG_SLOPE * v;
}

// ---------- GEMM1 + fused alpha1; h1 stored fp16 ----------
__global__ __launch_bounds__(256) void gemm1_kernel(
        const float* __restrict__ x, const float* __restrict__ W1,
        const float* __restrict__ att_s, const float* __restrict__ att_d,
        __half* __restrict__ h1, float* __restrict__ alpha_s,
        float* __restrict__ alpha_d) {
    __shared__ float ws[128 * 64];   // 32 KB
    __shared__ float xs[16 * 128];   // 8 KB
    const int tid = threadIdx.x;
    const int node0 = blockIdx.x * 16;
    for (int i = tid; i < 128 * 64; i += 256) ws[i] = W1[i];
    for (int i = tid; i < 16 * 128; i += 256) {
        int r = i >> 7, c = i & 127;
        int n = node0 + r;
        xs[i] = (n < NN) ? x[(long)n * 128 + c] : 0.f;
    }
    __syncthreads();
    const int ch = tid & 63;
    const int rbase = tid >> 6;      // wave id; wave owns nodes rbase+{0,4,8,12}
    float acc[4] = {0.f, 0.f, 0.f, 0.f};
    for (int k = 0; k < 128; ++k) {
        float w = ws[k * 64 + ch];
#pragma unroll
        for (int j = 0; j < 4; ++j)
            acc[j] += xs[(rbase + j * 4) * 128 + k] * w;
    }
    float ats = att_s[ch], atd = att_d[ch];
#pragma unroll
    for (int j = 0; j < 4; ++j) {
        int n = node0 + rbase + j * 4;
        h1[(long)n * 64 + ch] = __float2half_rn(acc[j]);
        float vs = acc[j] * ats;
        float vd = acc[j] * atd;
#pragma unroll
        for (int off = 1; off < 8; off <<= 1) {
            vs += __shfl_xor(vs, off, 64);
            vd += __shfl_xor(vd, off, 64);
        }
        if ((ch & 7) == 0) {
            alpha_s[n * 8 + (ch >> 3)] = vs;
            alpha_d[n * 8 + (ch >> 3)] = vd;
        }
    }
}

// ---------- CSR build: dst-range-partitioned degree histogram ----------
// range = blockIdx%8 (XCD round-robin heuristic): deg slice stays L2-local.
__global__ __launch_bounds__(256) void deg_hist_kernel(
        const int* __restrict__ ei, int* __restrict__ deg) {
    const int range = blockIdx.x & (NRANGE - 1);
    const int chunk = blockIdx.x >> 3;
    const int lo = range * RSIZE, hi = lo + RSIZE;
    const int base = chunk * CHUNK + threadIdx.x;
#pragma unroll
    for (int k = 0; k < EPT; ++k) {
        int e = base + k * 256;
        if (e >= ET) break;
        int d = (e < EE) ? ei[EE + e] : (e - EE);
        if (d >= lo && d < hi) atomicAdd(&deg[d], 1);
    }
}

// ---------- hierarchical scan phase 1: per-block sums ----------
__global__ __launch_bounds__(256) void scan_phase1(
        const int* __restrict__ deg, int* __restrict__ blocksum) {
    __shared__ int sh[256];
    int t = threadIdx.x;
    int i = blockIdx.x * 256 + t;
    sh[t] = (i < NN) ? deg[i] : 0;
    __syncthreads();
    for (int off = 128; off > 0; off >>= 1) {
        if (t < off) sh[t] += sh[t + off];
        __syncthreads();
    }
    if (t == 0) blocksum[blockIdx.x] = sh[0];
}

// ---------- phase 2: exclusive scan of block sums (1 block) ----------
__global__ __launch_bounds__(512) void scan_phase2(
        const int* __restrict__ blocksum, int* __restrict__ blockoff) {
    __shared__ int sh[512];
    int t = threadIdx.x;
    int v = (t < SCAN_NB) ? blocksum[t] : 0;
    sh[t] = v;
    __syncthreads();
    for (int off = 1; off < 512; off <<= 1) {
        int u = (t >= off) ? sh[t - off] : 0;
        __syncthreads();
        sh[t] += u;
        __syncthreads();
    }
    if (t < SCAN_NB) blockoff[t] = sh[t] - v;   // exclusive
}

// ---------- phase 3: intra-block exclusive scan + offset ----------
__global__ __launch_bounds__(256) void scan_phase3(
        const int* __restrict__ deg, const int* __restrict__ blockoff,
        int* __restrict__ rowptr, int* __restrict__ cursor) {
    __shared__ int sh[256];
    int t = threadIdx.x;
    int i = blockIdx.x * 256 + t;
    int d = (i < NN) ? deg[i] : 0;
    sh[t] = d;
    __syncthreads();
    for (int off = 1; off < 256; off <<= 1) {
        int u = (t >= off) ? sh[t - off] : 0;
        __syncthreads();
        sh[t] += u;
        __syncthreads();
    }
    if (i < NN) {
        int excl = blockoff[blockIdx.x] + sh[t] - d;
        rowptr[i] = excl;
        cursor[i] = excl;
        if (i == NN - 1) rowptr[NN] = excl + d;
    }
}

// ---------- CSR build: dst-range-partitioned scatter fill ----------
__global__ __launch_bounds__(256) void csr_fill_kernel(
        const int* __restrict__ ei, int* __restrict__ cursor,
        int* __restrict__ csr_src) {
    const int range = blockIdx.x & (NRANGE - 1);
    const int chunk = blockIdx.x >> 3;
    const int lo = range * RSIZE, hi = lo + RSIZE;
    const int base = chunk * CHUNK + threadIdx.x;
#pragma unroll
    for (int k = 0; k < EPT; ++k) {
        int e = base + k * 256;
        if (e >= ET) break;
        int s, d;
        if (e < EE) { s = ei[e]; d = ei[EE + e]; } else { s = d = e - EE; }
        if (d >= lo && d < hi) {
            int pos = atomicAdd(&cursor[d], 1);
            csr_src[pos] = s;
        }
    }
}

// ---------- conv1 fused: softmax-agg + ReLU/bias + gemm2 + rec pack ------
__global__ __launch_bounds__(256) void conv1_fused_kernel(
        const int* __restrict__ rowptr, const int* __restrict__ csr_src,
        const float* __restrict__ as1, const float* __restrict__ ad1,
        const __half* __restrict__ h1, const float* __restrict__ b1,
        const float* __restrict__ W2, const float* __restrict__ as2,
        const float* __restrict__ ad2, float4* __restrict__ rec) {
    long gid = (long)blockIdx.x * 256 + threadIdx.x;
    int n = (int)(gid >> 6);
    if (n >= NN) return;
    n = __builtin_amdgcn_readfirstlane(n);   // wave-uniform -> scalar loads
    int c = threadIdx.x & 63;
    int h = c >> 3;
    float adh = ad1[n * 8 + h];
    int jb = rowptr[n], je = rowptr[n + 1];
    float l0 = 0.f, l1 = 0.f, l2 = 0.f, l3 = 0.f;
    float a0 = 0.f, a1 = 0.f, a2 = 0.f, a3 = 0.f;
    int j = jb;
    for (; j + 3 < je; j += 4) {
        int s0 = csr_src[j], s1 = csr_src[j + 1];
        int s2 = csr_src[j + 2], s3 = csr_src[j + 3];
        float p0 = __expf(leaky(as1[s0 * 8 + h] + adh));
        float p1 = __expf(leaky(as1[s1 * 8 + h] + adh));
        float p2 = __expf(leaky(as1[s2 * 8 + h] + adh));
        float p3 = __expf(leaky(as1[s3 * 8 + h] + adh));
        l0 += p0; l1 += p1; l2 += p2; l3 += p3;
        a0 += p0 * __half2float(h1[(long)s0 * 64 + c]);
        a1 += p1 * __half2float(h1[(long)s1 * 64 + c]);
        a2 += p2 * __half2float(h1[(long)s2 * 64 + c]);
        a3 += p3 * __half2float(h1[(long)s3 * 64 + c]);
    }
    for (; j < je; ++j) {
        int s = csr_src[j];
        float p = __expf(leaky(as1[s * 8 + h] + adh));
        l0 += p;
        a0 += p * __half2float(h1[(long)s * 64 + c]);
    }
    float l = (l0 + l1) + (l2 + l3);
    float acc = (a0 + a1) + (a2 + a3);
    float o = acc / (l + 1e-16f);
    float a = o + b1[c];
    a = a > 0.f ? a : 0.f;                 // ReLU
    float r0 = a * W2[c * 2];
    float r1 = a * W2[c * 2 + 1];
#pragma unroll
    for (int off = 32; off > 0; off >>= 1) {
        r0 += __shfl_xor(r0, off, 64);
        r1 += __shfl_xor(r1, off, 64);
    }
    if (c == 0) {
        float s2v = r0 * as2[0] + r1 * as2[1];
        float d2v = r0 * ad2[0] + r1 * ad2[1];
        rec[n] = make_float4(s2v, r0, r1, d2v);   // (as2o, h2_0, h2_1, ad2o)
    }
}

// ---------- conv2 fused with mean-pool (LDS partials) ----------
__global__ __launch_bounds__(256) void conv2_pool_kernel(
        const int* __restrict__ rowptr, const int* __restrict__ csr_src,
        const float4* __restrict__ rec, const int* __restrict__ batch,
        float* __restrict__ pooled /*128 sums + 64 counts*/) {
    __shared__ float ls[192];
    int tid = threadIdx.x;
    if (tid < 192) ls[tid] = 0.f;
    __syncthreads();
    int n = blockIdx.x * 256 + tid;
    if (n < NN) {
        float adn = rec[n].w;
        int jb = rowptr[n], je = rowptr[n + 1];
        float l0 = 0.f, l1 = 0.f, x0 = 0.f, x1 = 0.f, y0 = 0.f, y1 = 0.f;
        int j = jb;
        for (; j + 1 < je; j += 2) {
            float4 ra = rec[csr_src[j]];
            float4 rb = rec[csr_src[j + 1]];
            float pa = __expf(leaky(ra.x + adn));
            float pb = __expf(leaky(rb.x + adn));
            l0 += pa; x0 += pa * ra.y; y0 += pa * ra.z;
            l1 += pb; x1 += pb * rb.y; y1 += pb * rb.z;
        }
        for (; j < je; ++j) {
            float4 ra = rec[csr_src[j]];
            float pa = __expf(leaky(ra.x + adn));
            l0 += pa; x0 += pa * ra.y; y0 += pa * ra.z;
        }
        float inv = 1.f / (l0 + l1 + 1e-16f);
        int g = batch[n];
        atomicAdd(&ls[g * 2],     (x0 + x1) * inv);
        atomicAdd(&ls[g * 2 + 1], (y0 + y1) * inv);
        atomicAdd(&ls[128 + g],   1.f);
    }
    __syncthreads();
    if (tid < 192) atomicAdd(&pooled[tid], ls[tid]);
}

// ---------- finalize: mean, +b2, log_softmax ----------
__global__ __launch_bounds__(64) void final_kernel(
        const float* __restrict__ pooled, const float* __restrict__ b2,
        float* __restrict__ out) {
    int g = threadIdx.x;
    if (g >= 64) return;
    float c = pooled[128 + g];
    float denom = c > 1.f ? c : 1.f;
    float p0 = pooled[g * 2] / denom + b2[0];
    float p1 = pooled[g * 2 + 1] / denom + b2[1];
    float m = fmaxf(p0, p1);
    float lse = m + logf(expf(p0 - m) + expf(p1 - m));
    out[g * 2] = p0 - lse;
    out[g * 2 + 1] = p1 - lse;
}

extern "C" void kernel_launch(void* const* d_in, const int* in_sizes, int n_in,
                              void* d_out, int out_size, void* d_ws, size_t ws_size,
                              hipStream_t stream) {
    const float* x   = (const float*)d_in[0];
    const int*   ei  = (const int*)d_in[1];     // [2,E] int32
    const int*   bat = (const int*)d_in[2];     // [N]
    const float* W1  = (const float*)d_in[3];
    const float* as1 = (const float*)d_in[4];
    const float* ad1 = (const float*)d_in[5];
    const float* b1  = (const float*)d_in[6];
    const float* W2  = (const float*)d_in[7];
    const float* as2 = (const float*)d_in[8];
    const float* ad2 = (const float*)d_in[9];
    const float* b2  = (const float*)d_in[10];
    float* out = (float*)d_out;

    float* ws = (float*)d_ws;
    // workspace layout (element offsets; off_rec 16B-aligned)
    const long off_h1     = 0;                          // N*64 halves = N*32 f
    const long off_as1    = off_h1   + (long)NN * 32;   // N*8
    const long off_ad1    = off_as1  + (long)NN * 8;    // N*8
    const long off_rec    = off_ad1  + (long)NN * 8;    // N*4 (float4)
    const long off_rowptr = off_rec  + (long)NN * 4;    // N+1 (int)
    const long off_cursor = off_rowptr + NN + 1;        // N   (int)
    const long off_csr    = off_cursor + NN;            // ET  (int)
    const long off_bsum   = off_csr + ET;               // SCAN_NB (int)
    const long off_boff   = off_bsum + SCAN_NB;         // SCAN_NB (int)
    const long off_zero   = off_boff + SCAN_NB;         // ---- zeroed ----
    const long off_deg    = off_zero;                   // N   (int)
    const long off_pool   = off_deg + NN;               // 192
    const long zero_elems = off_pool + 192 - off_zero;

    hipMemsetAsync(ws + off_zero, 0, zero_elems * sizeof(float), stream);

    gemm1_kernel<<<NN / 16, 256, 0, stream>>>(
        x, W1, as1, ad1, (__half*)(ws + off_h1), ws + off_as1, ws + off_ad1);

    const int rb = NCHUNK * NRANGE;
    deg_hist_kernel<<<rb, 256, 0, stream>>>(ei, (int*)(ws + off_deg));
    scan_phase1<<<SCAN_NB, 256, 0, stream>>>((const int*)(ws + off_deg),
                                             (int*)(ws + off_bsum));
    scan_phase2<<<1, 512, 0, stream>>>((const int*)(ws + off_bsum),
                                       (int*)(ws + off_boff));
    scan_phase3<<<SCAN_NB, 256, 0, stream>>>((const int*)(ws + off_deg),
                                             (const int*)(ws + off_boff),
                                             (int*)(ws + off_rowptr),
                                             (int*)(ws + off_cursor));
    csr_fill_kernel<<<rb, 256, 0, stream>>>(ei, (int*)(ws + off_cursor),
                                            (int*)(ws + off_csr));

    conv1_fused_kernel<<<(int)(((long)NN * 64 + 255) / 256), 256, 0, stream>>>(
        (const int*)(ws + off_rowptr), (const int*)(ws + off_csr),
        ws + off_as1, ws + off_ad1, (const __half*)(ws + off_h1), b1, W2,
        as2, ad2, (float4*)(ws + off_rec));

    conv2_pool_kernel<<<(NN + 255) / 256, 256, 0, stream>>>(
        (const int*)(ws + off_rowptr), (const int*)(ws + off_csr),
        (const float4*)(ws + off_rec), bat, ws + off_pool);

    final_kernel<<<1, 64, 0, stream>>>(ws + off_pool, b2, out);
}